// Round 1
// baseline (382.112 us; speedup 1.0000x reference)
//
#include <hip/hip_runtime.h>
#include <math.h>

#define N_CLASS   4432
#define GROUP_SZ  1108
#define NV4       (N_CLASS / 4)        // 1108 float4 chunks per row
#define GV4       (GROUP_SZ / 4)       // 277 chunks per group (group-aligned: 1108 = 4*277)
#define NROWS     16384
#define BLOCK     256
#define CPT       4                    // chunks c = tid + 256*i, i<4 always valid (max 1023)
#define TAIL_T    (NV4 - CPT * BLOCK)  // threads 0..83 own a 5th chunk (1024..1107)

static constexpr float CONF   = 0.9f;
static constexpr float SMOOTH = 0.1f / (GROUP_SZ - 1);   // 0.1/1107

typedef float v4f __attribute__((ext_vector_type(4)));

// Block-per-row (v2, was wave-per-row):
//  - 4 waves share one row -> only 5 live v4f per thread (20 VGPR data) instead of 18
//    (72 VGPR). __launch_bounds__(256,8) pins VGPR<=64 -> 32 waves/CU, 8 blocks/CU.
//  - plain cached loads (NT removed: the harness's 1.16 GB poison fill evicts L3
//    between restore and us, so NT's "avoid pollution" bought nothing and forfeited
//    L2 assistance).
//  - two tiny LDS reductions (max, then {s,gsum,xt}); resident blocks stagger each
//    other's barrier phases so the memory pipe never drains.
// loss = (m + log s) - ((CONF-SMOOTH)*x_t + SMOOTH*gsum)   [in-group smoothing folds
// to coefficient 1 on the log-normalizer: (CONF-SMOOTH) + SMOOTH*GROUP_SZ = 1]
template <bool WS_MODE>
__global__ __launch_bounds__(BLOCK, 8)
void lsl_kernel(const float* __restrict__ logits,
                const int*   __restrict__ target,
                float*       __restrict__ sink) {
    const int tid = threadIdx.x;
    const int row = (NROWS - 1) - blockIdx.x;   // reverse order: harmless, keeps any
                                                // restore-tail L3 warmth if present
    const v4f* __restrict__ rp = (const v4f*)(logits + (size_t)row * N_CLASS);

    // ---- issue all loads first: 4-5 float4 per thread, cached ----
    v4f v[CPT + 1];
    #pragma unroll
    for (int i = 0; i < CPT; ++i) v[i] = rp[tid + BLOCK * i];
    const bool have5 = (tid < TAIL_T);
    v[CPT] = (v4f){-INFINITY, -INFINITY, -INFINITY, -INFINITY};
    if (have5) v[CPT] = rp[tid + BLOCK * CPT];

    const int t      = target[row];             // block-uniform
    const int g      = t / GROUP_SZ;
    const int glo    = g * GV4;                 // group chunk range [glo, ghi)
    const int ghi    = glo + GV4;
    const int tchunk = t >> 2;
    const int tlane  = t & 3;

    // ---- phase 1: block max (wave butterfly + 4-slot LDS) ----
    float m = -INFINITY;
    #pragma unroll
    for (int i = 0; i <= CPT; ++i)
        m = fmaxf(m, fmaxf(fmaxf(v[i].x, v[i].y), fmaxf(v[i].z, v[i].w)));
    #pragma unroll
    for (int off = 32; off > 0; off >>= 1)
        m = fmaxf(m, __shfl_xor(m, off));

    __shared__ float sm[4];
    __shared__ float sr[4][3];
    const int wave = tid >> 6, lane = tid & 63;
    if (lane == 0) sm[wave] = m;
    __syncthreads();
    m = fmaxf(fmaxf(sm[0], sm[1]), fmaxf(sm[2], sm[3]));   // wave-uniform block max

    // ---- phase 2: exp-sum + group-sum + target pick (all from registers) ----
    float s = 0.f, gsum = 0.f, xt = 0.f;
    #pragma unroll
    for (int i = 0; i <= CPT; ++i) {
        s += __expf(v[i].x - m) + __expf(v[i].y - m)
           + __expf(v[i].z - m) + __expf(v[i].w - m);      // invalid tail: exp(-inf)=0
        const int  c     = tid + BLOCK * i;
        const bool valid = (i < CPT) || have5;
        if (valid && c >= glo && c < ghi)
            gsum += (v[i].x + v[i].y) + (v[i].z + v[i].w);
        if (valid && c == tchunk)
            xt = (tlane == 0) ? v[i].x : (tlane == 1) ? v[i].y
               : (tlane == 2) ? v[i].z : v[i].w;
    }
    #pragma unroll
    for (int off = 32; off > 0; off >>= 1) {
        s    += __shfl_xor(s, off);
        gsum += __shfl_xor(gsum, off);
        xt   += __shfl_xor(xt, off);            // only the owning lane is nonzero
    }
    if (lane == 0) { sr[wave][0] = s; sr[wave][1] = gsum; sr[wave][2] = xt; }
    __syncthreads();
    if (tid == 0) {
        s    = (sr[0][0] + sr[1][0]) + (sr[2][0] + sr[3][0]);
        gsum = (sr[0][1] + sr[1][1]) + (sr[2][1] + sr[3][1]);
        xt   = (sr[0][2] + sr[1][2]) + (sr[2][2] + sr[3][2]);
        const float loss = (m + __logf(s)) - ((CONF - SMOOTH) * xt + SMOOTH * gsum);
        if (WS_MODE) sink[row] = loss;
        else         atomicAdd(sink, loss * (1.0f / NROWS));
    }
}

// One block: reduce NROWS floats from ws -> mean into out[0].
__global__ __launch_bounds__(256)
void lsl_reduce(const float* __restrict__ ws, float* __restrict__ out) {
    const float4* wp = (const float4*)ws;
    const int tid = threadIdx.x;
    float s = 0.f;
    #pragma unroll
    for (int i = 0; i < NROWS / 4 / 256; ++i) {       // 16 iters
        float4 v = wp[tid + i * 256];
        s += (v.x + v.y) + (v.z + v.w);
    }
    #pragma unroll
    for (int off = 32; off > 0; off >>= 1) s += __shfl_xor(s, off);
    __shared__ float ss[4];
    const int wave = tid >> 6, lane = tid & 63;
    if (lane == 0) ss[wave] = s;
    __syncthreads();
    if (tid == 0) out[0] = ((ss[0] + ss[1]) + (ss[2] + ss[3])) * (1.0f / NROWS);
}

extern "C" void kernel_launch(void* const* d_in, const int* in_sizes, int n_in,
                              void* d_out, int out_size, void* d_ws, size_t ws_size,
                              hipStream_t stream) {
    const float* logits = (const float*)d_in[0];
    const int*   target = (const int*)d_in[1];
    float*       result = (float*)d_out;
    float*       ws     = (float*)d_ws;

    if (ws_size >= (size_t)NROWS * sizeof(float)) {
        lsl_kernel<true><<<NROWS, BLOCK, 0, stream>>>(logits, target, ws);
        lsl_reduce<<<1, 256, 0, stream>>>(ws, result);
    } else {
        hipMemsetAsync(result, 0, sizeof(float), stream);
        lsl_kernel<false><<<NROWS, BLOCK, 0, stream>>>(logits, target, result);
    }
}